// Round 5
// baseline (722.843 us; speedup 1.0000x reference)
//
#include <hip/hip_runtime.h>
#include <math.h>

#define NN 12800
#define NE 204800
#define LL 24
#define HH 128
#define BB 64
#define RR 8
#define VAx 20
#define KC 1152  // R*H + H
#define CHK 8    // node chunks per batch for aggS
#define NBLK 32  // dst nodes per k_aggF block
#define AGG_LDS (NBLK * RR * HH * 4 + NBLK * RR * 4)  // 132096 B

typedef __attribute__((ext_vector_type(8))) short bf16x8;
typedef __attribute__((ext_vector_type(4))) float f32x4;

__device__ inline unsigned short f2bf(float f) {
  unsigned u = __float_as_uint(f);
  unsigned r = u + 0x7FFF + ((u >> 16) & 1);  // RNE
  return (unsigned short)(r >> 16);
}
__device__ inline float bf2f(unsigned short s) {
  return __uint_as_float(((unsigned)s) << 16);
}
__device__ inline unsigned packbf(float lo, float hi) {
  return (unsigned)f2bf(lo) | ((unsigned)f2bf(hi) << 16);
}

// ---------------- mega prep: all weight transforms + embed + zeroing, 1 launch ----------------
__global__ void k_prep(const float* __restrict__ rgcnW, const float* __restrict__ rgcnRoot,
                       unsigned short* __restrict__ wcatT,
                       const float* __restrict__ linN_w, unsigned short* __restrict__ linN2bt,
                       const float* __restrict__ Wih, float* __restrict__ WihT,
                       const float* __restrict__ Whh, float* __restrict__ WhhT,
                       const float* __restrict__ linA_w, float* __restrict__ linAT,
                       const float* __restrict__ fin_w, float* __restrict__ finT,
                       float* __restrict__ linN1T,
                       const int* __restrict__ nt, const float* __restrict__ embN,
                       unsigned int* __restrict__ x, int* __restrict__ bcnt) {
  int idx = blockIdx.x * 256 + threadIdx.x;
  if (idx < HH * KC) {  // wcatT[d][k]
    int d = idx / KC, k = idx - d * KC;
    float v = (k < 1024) ? rgcnW[(k >> 7) * (HH * HH) + (k & 127) * HH + d]
                         : rgcnRoot[(k - 1024) * HH + d];
    wcatT[idx] = f2bf(v);
    return;
  }
  idx -= HH * KC;
  if (idx < HH * HH) {  // linN2bt[d][k] = linN_w[d][128+k]
    int d = idx >> 7, k = idx & 127;
    linN2bt[idx] = f2bf(linN_w[d * 2 * HH + HH + k]);
    return;
  }
  idx -= HH * HH;
  if (idx < 3 * HH * HH) {  // WihT[c*384+r] = Wih[r*128+c]
    int r = idx / HH, c = idx - r * HH;
    WihT[c * 384 + r] = Wih[r * HH + c];
    return;
  }
  idx -= 3 * HH * HH;
  if (idx < 3 * HH * HH) {  // WhhT
    int r = idx / HH, c = idx - r * HH;
    WhhT[c * 384 + r] = Whh[r * HH + c];
    return;
  }
  idx -= 3 * HH * HH;
  if (idx < HH * HH) {  // linAT
    int r = idx >> 7, c = idx & 127;
    linAT[c * HH + r] = linA_w[r * HH + c];
    return;
  }
  idx -= HH * HH;
  if (idx < HH * HH) {  // finT
    int r = idx >> 7, c = idx & 127;
    finT[c * HH + r] = fin_w[r * HH + c];
    return;
  }
  idx -= HH * HH;
  if (idx < HH * HH) {  // linN1T[c*128+r] = linN_w[r][c]
    int r = idx >> 7, c = idx & 127;
    linN1T[c * HH + r] = linN_w[r * 2 * HH + c];
    return;
  }
  idx -= HH * HH;
  if (idx < NN * 64) {  // embed -> bf16 pairs
    int n = idx >> 6, p = idx & 63;
    const float* e = embN + (size_t)nt[n] * HH + p * 2;
    x[idx] = packbf(e[0], e[1]);
    return;
  }
  idx -= NN * 64;
  if (idx < BB) bcnt[idx] = 0;
}
#define PREP_TOTAL (HH * KC + HH * HH + 3 * HH * HH + 3 * HH * HH + HH * HH + HH * HH + HH * HH + NN * 64 + BB)

// ---- batch CSR (decorrelated iteration: n = (i&63)*200 + i/64 is a bijection on 12800) ----
__global__ void k_countb(const int* __restrict__ bs, int* __restrict__ bcnt) {
  int i = blockIdx.x * 256 + threadIdx.x;
  if (i >= NN) return;
  int n = (i & 63) * (NN / 64) + (i >> 6);
  atomicAdd(&bcnt[bs[n]], 1);
}

__global__ void k_scanb(const int* __restrict__ bcnt, int* __restrict__ bptr,
                        int* __restrict__ bcur) {
  int lane = threadIdx.x;  // 64 threads
  int v = bcnt[lane];
  int incl = v;
#pragma unroll
  for (int off = 1; off < 64; off <<= 1) {
    int t = __shfl_up(incl, off);
    if (lane >= off) incl += t;
  }
  bptr[lane] = incl - v;
  bcur[lane] = incl - v;
  if (lane == 63) bptr[BB] = incl;
}

__global__ void k_scatb(const int* __restrict__ bs, int* __restrict__ bcur,
                        int* __restrict__ bnodes) {
  int i = blockIdx.x * 256 + threadIdx.x;
  if (i >= NN) return;
  int n = (i & 63) * (NN / 64) + (i >> 6);
  int p = atomicAdd(&bcur[bs[n]], 1);
  bnodes[p] = n;
}

// ---------------- RGCN aggregation: scan-all edges, LDS accumulators ----------------
// Block owns NBLK dst nodes. Streams the whole edge list (edst int4/lane, prefetched),
// ballot-filters for its range, ds_add_f32 gathers of x[src] into LDS.
// Writes A rows [node][576 pairs]: 512 rel-mean pairs + 64 root pairs.
__global__ __launch_bounds__(256) void k_aggF(const unsigned int* __restrict__ x,
                                              const int* __restrict__ esrc,
                                              const int* __restrict__ edst,
                                              const int* __restrict__ erel,
                                              unsigned int* __restrict__ A,
                                              int n0chunk, int nc) {
  extern __shared__ float accS[];  // [NBLK*RR][HH] fp32 + cnt[NBLK*RR]
  int* cntS = (int*)(accS + NBLK * RR * HH);
  int tid = threadIdx.x;
  int nbase = n0chunk + blockIdx.x * NBLK;
  for (int i = tid; i < NBLK * RR * HH; i += 256) accS[i] = 0.f;
  for (int i = tid; i < NBLK * RR; i += 256) cntS[i] = 0;
  __syncthreads();
  int lane = tid & 63, w = tid >> 6;

  const int EPW = NE / 4;           // edges per wave
  const int IT = EPW / 256;         // int4-iterations per wave
  const int4* ep = (const int4*)edst + (size_t)w * (EPW / 4);
  int4 nx = ep[lane];
  for (int it = 0; it < IT; ++it) {
    int4 d4 = nx;
    if (it < IT - 1) nx = ep[(it + 1) * 64 + lane];
    int ebase = w * EPW + it * 256;
#pragma unroll
    for (int c = 0; c < 4; ++c) {
      int dval = (c == 0) ? d4.x : (c == 1) ? d4.y : (c == 2) ? d4.z : d4.w;
      unsigned long long m = __ballot((unsigned)(dval - nbase) < (unsigned)NBLK);
      while (m) {
        int l = __ffsll(m) - 1;
        m &= m - 1;
        int dd = __shfl(dval, l);
        int ee = __builtin_amdgcn_readfirstlane(ebase + l * 4 + c);
        int sr = __builtin_amdgcn_readfirstlane(esrc[ee]);
        int rr = __builtin_amdgcn_readfirstlane(erel[ee]);
        unsigned pv = x[(size_t)sr * 64 + lane];
        int row = (dd - nbase) * RR + rr;
        float* ap = accS + (size_t)row * HH + lane * 2;
        atomicAdd(ap, bf2f((unsigned short)(pv & 0xFFFF)));
        atomicAdd(ap + 1, bf2f((unsigned short)(pv >> 16)));
        if (lane == 0) atomicAdd(&cntS[row], 1);
      }
    }
  }
  __syncthreads();
  // epilogue: A[node][pair p]: p<512 -> rel means, p>=512 -> root copy
  for (int n = 0; n < NBLK; ++n) {
    for (int p = tid; p < 576; p += 256) {
      unsigned outv;
      if (p < 512) {
        int rel = p >> 6, fp = p & 63;
        int row = n * RR + rel;
        int cc = cntS[row];
        float inv = 1.0f / (float)(cc > 0 ? cc : 1);
        float v0 = accS[(size_t)row * HH + fp * 2] * inv;
        float v1 = accS[(size_t)row * HH + fp * 2 + 1] * inv;
        outv = packbf(v0, v1);
      } else {
        outv = x[(size_t)(nbase + n) * 64 + (p - 512)];
      }
      A[(size_t)(nbase - n0chunk + n) * 576 + p] = outv;
    }
  }
}

// ---------------- bf16 MFMA GEMM: C[M,128] = A[M,K](bf16) * B[K,128] ----------------
template <int OUTMODE>
__global__ __launch_bounds__(256) void k_mgemm(const unsigned short* __restrict__ Abf, int lda,
                                               const unsigned short* __restrict__ BTbf, int ldb,
                                               const float* __restrict__ bias,
                                               void* __restrict__ C, int M, int K) {
  __shared__ unsigned int ldsu[(8192 + 16384) / 4];
  char* ldsc = (char*)ldsu;
  int tid = threadIdx.x;
  int m0 = blockIdx.x * 64;
  int w = tid >> 6, l = tid & 63;
  int lrow = l & 15, lg = l >> 4;
  f32x4 acc[8] = {};

  const char* Ab = (const char*)Abf;
  const char* Bb = (const char*)BTbf;
  int KT = K >> 6;
  for (int kt = 0; kt < KT; ++kt) {
    int k0 = kt << 6;
#pragma unroll
    for (int i = 0; i < 2; ++i) {
      int slot = i * 256 + tid;
      int row = slot >> 3;
      int colb = (slot & 7) << 4;
      int gr = m0 + row;
      gr = gr < M ? gr : M - 1;
      size_t srcb = ((size_t)gr * lda + k0) * 2 + (size_t)(colb ^ ((row & 7) << 4));
      __builtin_amdgcn_global_load_lds((const unsigned int*)(Ab + srcb),
                                       (unsigned int*)(ldsc + slot * 16), 16, 0, 0);
    }
#pragma unroll
    for (int i = 0; i < 4; ++i) {
      int slot = i * 256 + tid;
      int row = slot >> 3;
      int colb = (slot & 7) << 4;
      size_t srcb = ((size_t)row * ldb + k0) * 2 + (size_t)(colb ^ ((row & 7) << 4));
      __builtin_amdgcn_global_load_lds((const unsigned int*)(Bb + srcb),
                                       (unsigned int*)(ldsc + 8192 + slot * 16), 16, 0, 0);
    }
    __syncthreads();
#pragma unroll
    for (int h = 0; h < 2; ++h) {
      int arow = w * 16 + lrow;
      bf16x8 af = *(const bf16x8*)(ldsc + arow * 128 +
                                   ((h * 64 + lg * 16) ^ ((arow & 7) << 4)));
#pragma unroll
      for (int c = 0; c < 8; ++c) {
        int brow = c * 16 + lrow;
        bf16x8 bf = *(const bf16x8*)(ldsc + 8192 + brow * 128 +
                                     ((h * 64 + lg * 16) ^ ((brow & 7) << 4)));
        acc[c] = __builtin_amdgcn_mfma_f32_16x16x32_bf16(af, bf, acc[c], 0, 0, 0);
      }
    }
    __syncthreads();
  }
#pragma unroll
  for (int c = 0; c < 8; ++c) {
#pragma unroll
    for (int r = 0; r < 4; ++r) {
      int gm = m0 + w * 16 + lg * 4 + r;
      if (gm >= M) continue;
      int gn = c * 16 + lrow;
      float v = acc[c][r];
      if (OUTMODE == 1) {
        v = fmaxf(v + bias[gn], 0.f);
        ((unsigned short*)C)[(size_t)gm * HH + gn] = f2bf(v);
      } else {
        ((float*)C)[(size_t)gm * HH + gn] = v;
      }
    }
  }
}

// ---------------- generic fp32 tiled GEMM (small GEMMs) ----------------
template <bool BIAS, bool RELU>
__global__ __launch_bounds__(256) void k_gemm(const float* __restrict__ Am, int lda,
                                              const float* __restrict__ Bm, int ldb,
                                              const float* __restrict__ bias,
                                              float* __restrict__ C, int ldc,
                                              int M, int Nc, int K) {
  __shared__ float As[16][65];
  __shared__ float Bs[16][65];
  int m0 = blockIdx.y * 64, n0 = blockIdx.x * 64;
  int tx = threadIdx.x & 15, ty = threadIdx.x >> 4;
  float acc[4][4] = {};
  for (int k0 = 0; k0 < K; k0 += 16) {
#pragma unroll
    for (int i = 0; i < 4; ++i) {
      int idx = threadIdx.x + i * 256;
      int kk = idx & 15, mm = idx >> 4;
      int gm = m0 + mm, gk = k0 + kk;
      As[kk][mm] = (gm < M && gk < K) ? Am[(size_t)gm * lda + gk] : 0.f;
    }
#pragma unroll
    for (int i = 0; i < 4; ++i) {
      int idx = threadIdx.x + i * 256;
      int nn = idx & 63, kk = idx >> 6;
      int gk = k0 + kk, gn = n0 + nn;
      Bs[kk][nn] = (gk < K && gn < Nc) ? Bm[(size_t)gk * ldb + gn] : 0.f;
    }
    __syncthreads();
#pragma unroll
    for (int kk = 0; kk < 16; ++kk) {
      float a[4], b[4];
#pragma unroll
      for (int i = 0; i < 4; ++i) a[i] = As[kk][ty * 4 + i];
#pragma unroll
      for (int j = 0; j < 4; ++j) b[j] = Bs[kk][tx * 4 + j];
#pragma unroll
      for (int i = 0; i < 4; ++i)
#pragma unroll
        for (int j = 0; j < 4; ++j) acc[i][j] = fmaf(a[i], b[j], acc[i][j]);
    }
    __syncthreads();
  }
#pragma unroll
  for (int i = 0; i < 4; ++i) {
    int gm = m0 + ty * 4 + i;
    if (gm >= M) continue;
#pragma unroll
    for (int j = 0; j < 4; ++j) {
      int gn = n0 + tx * 4 + j;
      if (gn >= Nc) continue;
      float v = acc[i][j];
      if (BIAS) v += bias[gn];
      if (RELU) v = fmaxf(v, 0.f);
      C[(size_t)gm * ldc + gn] = v;
    }
  }
}

// ---------------- aggS partials: 512 blocks (64 batches x 8 chunks) ----------------
__global__ __launch_bounds__(256) void k_aggS_part(const float* __restrict__ seqin,
                                                   const unsigned short* __restrict__ x,
                                                   const int* __restrict__ bptr,
                                                   const int* __restrict__ bnodes,
                                                   float* __restrict__ part) {
  int bc = blockIdx.x, b = bc >> 3, c = bc & 7;
  int h = threadIdx.x & 127, l0 = threadIdx.x >> 7;  // l0 in {0,1}
  int i0 = bptr[b], i1 = bptr[b + 1];
  int len = i1 - i0;
  int per = (len + CHK - 1) / CHK;
  int j0 = i0 + c * per;
  int j1 = j0 + per;
  if (j1 > i1) j1 = i1;
  float acc[12] = {};
  float esum = 0.f;
  for (int i = j0; i < j1; ++i) {
    int n = bnodes[i];
    float e = bf2f(x[n * HH + h]);
    esum += e;
    const float* srow = seqin + (size_t)n * LL;
#pragma unroll
    for (int t = 0; t < 12; ++t) acc[t] = fmaf(srow[l0 + 2 * t], e, acc[t]);
  }
  float* p = part + (size_t)bc * 25 * HH + h;
#pragma unroll
  for (int t = 0; t < 12; ++t) p[(l0 + 2 * t) * HH] = acc[t];
  if (l0 == 0) p[24 * HH] = esum;
}

// reduce partials; writes ig (with SOS at t=0) and hG
__global__ void k_aggS_red(const float* __restrict__ part, const int* __restrict__ bptr,
                           const float* __restrict__ embA, const int* __restrict__ act,
                           float* __restrict__ ig, float* __restrict__ hG) {
  int idx = blockIdx.x * 256 + threadIdx.x;
  if (idx >= BB * 25 * HH) return;
  int h = idx & 127;
  int rem = idx >> 7;
  int l = rem % 25, b = rem / 25;
  if (l == 23) {  // agg[23] is dropped by [:, :L]; reuse slot for ig[b][0] = SOS
    ig[((size_t)b * LL) * HH + h] = embA[(size_t)act[b] * HH + h];
    return;
  }
  float s = 0.f;
#pragma unroll
  for (int c = 0; c < CHK; ++c) s += part[(((size_t)(b * CHK + c)) * 25 + l) * HH + h];
  if (l == 24) {
    int len = bptr[b + 1] - bptr[b];
    hG[b * HH + h] = s / (float)len;
  } else {
    ig[((size_t)b * LL + l + 1) * HH + h] = s;
  }
}

// ---------------- merged heads ----------------
__global__ __launch_bounds__(128) void k_heads(const float* __restrict__ hG,
                                               const float* __restrict__ linAT,
                                               const float* __restrict__ linA_b,
                                               const float* __restrict__ linAf_w,
                                               const float* __restrict__ linAf_b,
                                               const float* __restrict__ finT,
                                               const float* __restrict__ fin_b,
                                               const float* __restrict__ finf_w,
                                               const float* __restrict__ finf_b,
                                               float* __restrict__ outA,
                                               float* __restrict__ outF) {
  int b = blockIdx.x >> 1, which = blockIdx.x & 1, j = threadIdx.x;
  __shared__ float hsh[HH], t1[HH];
  hsh[j] = hG[b * HH + j];
  __syncthreads();
  const float* Wt = which ? finT : linAT;
  const float* bb = which ? fin_b : linA_b;
  float s = bb[j];
  for (int k = 0; k < HH; ++k) s = fmaf(hsh[k], Wt[k * HH + j], s);
  t1[j] = fmaxf(s, 0.f);
  __syncthreads();
  if (which == 0) {
    if (j < VAx) {
      float o = linAf_b[j];
      for (int k = 0; k < HH; ++k) o = fmaf(t1[k], linAf_w[j * HH + k], o);
      outA[b * VAx + j] = o;
    }
  } else if (j == 0) {
    float o = finf_b[0];
    for (int k = 0; k < HH; ++k) o = fmaf(t1[k], finf_w[k], o);
    outF[b] = 1.f / (1.f + expf(-o));
  }
}

// ---------------- GRU: 64 blocks x 384 threads, Whh column in registers ----------------
__global__ __launch_bounds__(384) void k_gru(const float* __restrict__ gi,
                                             const float* __restrict__ WhhT,  // [128][384]
                                             const float* __restrict__ bhh,
                                             const float* __restrict__ hG,
                                             float* __restrict__ seqout) {
  int b = blockIdx.x, tid = threadIdx.x;
  int gate = tid >> 7, j = tid & 127;
  __shared__ float h[HH];
  __shared__ float sz[HH], sg[HH];
  float w[HH];
#pragma unroll
  for (int k = 0; k < HH; ++k) w[k] = WhhT[k * 384 + tid];
  float bh = bhh[tid];
  if (tid < HH) h[tid] = hG[b * HH + tid];
  __syncthreads();
  const float* gib = gi + (size_t)b * LL * 384;
  for (int t = 0; t < LL; ++t) {
    float giv = gib[t * 384 + tid];
    float gin = (gate == 0) ? gib[t * 384 + 256 + j] : 0.f;  // wave-uniform branch
    float hj = h[j];
    float g0 = 0.f, g1 = 0.f, g2 = 0.f, g3 = 0.f;
    const float4* h4 = (const float4*)h;
#pragma unroll
    for (int k4 = 0; k4 < HH / 4; ++k4) {
      float4 hv = h4[k4];
      g0 = fmaf(w[4 * k4 + 0], hv.x, g0);
      g1 = fmaf(w[4 * k4 + 1], hv.y, g1);
      g2 = fmaf(w[4 * k4 + 2], hv.z, g2);
      g3 = fmaf(w[4 * k4 + 3], hv.w, g3);
    }
    float g = bh + ((g0 + g1) + (g2 + g3));
    float r = 0.f;
    if (gate == 0) {
      r = 1.f / (1.f + expf(-(giv + g)));
    } else if (gate == 1) {
      sz[j] = 1.f / (1.f + expf(-(giv + g)));
    } else {
      sg[j] = g;
    }
    __syncthreads();
    if (gate == 0) {
      float n = tanhf(gin + r * sg[j]);
      float z = sz[j];
      float hn = (1.f - z) * n + z * hj;
      h[j] = hn;
      seqout[((size_t)b * LL + t) * HH + j] = hn;
    }
    __syncthreads();
  }
}

// ---------------- fused logits ----------------
__global__ __launch_bounds__(256) void k_logits(const float* __restrict__ part1,
                                                const float* __restrict__ part2,
                                                const float* __restrict__ linN_b,
                                                const float* __restrict__ linNf_w,
                                                const float* __restrict__ linNf_b,
                                                const int* __restrict__ bs,
                                                float* __restrict__ logits) {
  int wid = ((blockIdx.x * 256) + threadIdx.x) >> 6;
  int lane = threadIdx.x & 63;
  if (wid >= NN) return;
  int n = wid;
  int b = bs[n];
  float p2a = part2[n * HH + lane] + linN_b[lane];
  float p2b = part2[n * HH + 64 + lane] + linN_b[64 + lane];
  float wa = linNf_w[lane], wb = linNf_w[64 + lane];
  const float* p1 = part1 + (size_t)b * LL * HH;
  float bf = linNf_b[0];
  for (int l = 0; l < LL; ++l) {
    float v = fmaxf(p1[l * HH + lane] + p2a, 0.f) * wa +
              fmaxf(p1[l * HH + 64 + lane] + p2b, 0.f) * wb;
#pragma unroll
    for (int off = 32; off > 0; off >>= 1) v += __shfl_down(v, off);
    if (lane == 0) logits[n * LL + l] = v + bf;
  }
}

// ---------------- segment softmax ----------------
__global__ __launch_bounds__(64) void k_softmax(const float* __restrict__ logits,
                                                const int* __restrict__ bptr,
                                                const int* __restrict__ bnodes,
                                                float* __restrict__ outN) {
  int b = blockIdx.x / LL, l = blockIdx.x % LL;
  int lane = threadIdx.x;
  int i0 = bptr[b], i1 = bptr[b + 1];
  float m = -1e30f;
  for (int i = i0 + lane; i < i1; i += 64) m = fmaxf(m, logits[bnodes[i] * LL + l]);
#pragma unroll
  for (int off = 32; off > 0; off >>= 1) m = fmaxf(m, __shfl_xor(m, off));
  float s = 0.f;
  for (int i = i0 + lane; i < i1; i += 64) s += expf(logits[bnodes[i] * LL + l] - m);
#pragma unroll
  for (int off = 32; off > 0; off >>= 1) s += __shfl_xor(s, off);
  float inv = 1.f / s;
  for (int i = i0 + lane; i < i1; i += 64) {
    int n = bnodes[i];
    outN[n * LL + l] = expf(logits[n * LL + l] - m) * inv;
  }
}

// ---------------- host ----------------
extern "C" void kernel_launch(void* const* d_in, const int* in_sizes, int n_in,
                              void* d_out, int out_size, void* d_ws, size_t ws_size,
                              hipStream_t stream) {
  const int* nodeTypes = (const int*)d_in[0];
  const int* esrc = (const int*)d_in[1];
  const int* edst = esrc + NE;
  const int* erel = (const int*)d_in[2];
  const int* bs = (const int*)d_in[3];
  const float* seqin = (const float*)d_in[4];
  const int* actin = (const int*)d_in[7];
  const float* embN = (const float*)d_in[8];
  const float* embA = (const float*)d_in[9];
  const float* rgcnW = (const float*)d_in[10];
  const float* rgcnRoot = (const float*)d_in[11];
  const float* rgcnB = (const float*)d_in[12];
  const float* Wih = (const float*)d_in[13];
  const float* Whh = (const float*)d_in[14];
  const float* bih = (const float*)d_in[15];
  const float* bhh = (const float*)d_in[16];
  const float* linA_w = (const float*)d_in[17];
  const float* linA_b = (const float*)d_in[18];
  const float* linAf_w = (const float*)d_in[19];
  const float* linAf_b = (const float*)d_in[20];
  const float* linN_w = (const float*)d_in[21];
  const float* linN_b = (const float*)d_in[22];
  const float* linNf_w = (const float*)d_in[23];
  const float* linNf_b = (const float*)d_in[24];
  const float* fin_w = (const float*)d_in[25];
  const float* fin_b = (const float*)d_in[26];
  const float* finf_w = (const float*)d_in[27];
  const float* finf_b = (const float*)d_in[28];

  float* outA = (float*)d_out;
  float* outNodes = outA + BB * VAx;
  float* outF = outNodes + (size_t)NN * LL;

  // allow >64KB dynamic LDS for k_aggF (idempotent host call; safe during capture)
  hipFuncSetAttribute((const void*)k_aggF, hipFuncAttributeMaxDynamicSharedMemorySize,
                      AGG_LDS);

  char* basep = (char*)d_ws;
  size_t off = 0;
  auto alloc = [&](size_t bytes) -> void* {
    void* p = basep + off;
    off = (off + bytes + 255) & ~(size_t)255;
    return p;
  };

  unsigned int* x = (unsigned int*)alloc(sizeof(unsigned int) * NN * 64);   // bf16 pairs
  unsigned int* x2 = (unsigned int*)alloc(sizeof(unsigned int) * NN * 64);  // bf16 pairs
  float* hG = (float*)alloc(sizeof(float) * BB * HH);
  unsigned short* wcatT = (unsigned short*)alloc(sizeof(unsigned short) * HH * KC);
  unsigned short* linN2bt = (unsigned short*)alloc(sizeof(unsigned short) * HH * HH);
  float* WihT = (float*)alloc(sizeof(float) * HH * 3 * HH);
  float* WhhT = (float*)alloc(sizeof(float) * HH * 3 * HH);
  float* linAT = (float*)alloc(sizeof(float) * HH * HH);
  float* finT = (float*)alloc(sizeof(float) * HH * HH);
  float* linN1T = (float*)alloc(sizeof(float) * HH * HH);
  float* part = (float*)alloc(sizeof(float) * BB * CHK * 25 * HH);
  float* ig = (float*)alloc(sizeof(float) * BB * LL * HH);
  float* gi = (float*)alloc(sizeof(float) * BB * LL * 3 * HH);
  float* seq = (float*)alloc(sizeof(float) * BB * LL * HH);
  float* part1 = (float*)alloc(sizeof(float) * BB * LL * HH);
  float* part2 = (float*)alloc(sizeof(float) * NN * HH);
  float* logitsB = (float*)alloc(sizeof(float) * NN * LL);
  int* bcnt = (int*)alloc(sizeof(int) * BB);
  int* bptr = (int*)alloc(sizeof(int) * (BB + 1));
  int* bcur = (int*)alloc(sizeof(int) * BB);
  int* bnodes = (int*)alloc(sizeof(int) * NN);

  size_t remain = (ws_size > off) ? (ws_size - off) : 0;
  int NCk = NN;
  while ((size_t)NCk * KC * 2 > remain && NCk > 100) NCk >>= 1;
  unsigned int* A = (unsigned int*)alloc((size_t)NCk * (KC / 2) * sizeof(unsigned int));

  // ---- prep (1 launch): weight transforms, embed, zero bcnt ----
  k_prep<<<(PREP_TOTAL + 255) / 256, 256, 0, stream>>>(
      rgcnW, rgcnRoot, wcatT, linN_w, linN2bt, Wih, WihT, Whh, WhhT, linA_w, linAT,
      fin_w, finT, linN1T, nodeTypes, embN, x, bcnt);

  // ---- batch CSR (small, decorrelated atomics) ----
  k_countb<<<(NN + 255) / 256, 256, 0, stream>>>(bs, bcnt);
  k_scanb<<<1, 64, 0, stream>>>(bcnt, bptr, bcur);
  k_scatb<<<(NN + 255) / 256, 256, 0, stream>>>(bs, bcur, bnodes);

  // ---- 2 RGCN layers (shared weights): scan-all LDS agg + bf16 MFMA ----
  const unsigned int* xin = x;
  unsigned int* xout = x2;
  for (int layer = 0; layer < 2; ++layer) {
    for (int n0 = 0; n0 < NN; n0 += NCk) {
      int nc = NN - n0 < NCk ? NN - n0 : NCk;
      k_aggF<<<nc / NBLK, 256, AGG_LDS, stream>>>(xin, esrc, edst, erel, A, n0, nc);
      k_mgemm<1><<<(nc + 63) / 64, 256, 0, stream>>>(
          (const unsigned short*)A, KC, wcatT, KC, rgcnB,
          (void*)((unsigned short*)xout + (size_t)n0 * HH), nc, KC);
    }
    const unsigned int* t = xin;
    xin = xout;
    xout = (unsigned int*)t;
  }
  const unsigned short* nodeEmb = (const unsigned short*)xin;

  // ---- aggS partial/reduce: produces ig (with SOS) and hG ----
  k_aggS_part<<<BB * CHK, 256, 0, stream>>>(seqin, nodeEmb, bptr, bnodes, part);
  k_aggS_red<<<(BB * 25 * HH + 255) / 256, 256, 0, stream>>>(part, bptr, embA, actin, ig, hG);

  // ---- heads ----
  k_heads<<<2 * BB, HH, 0, stream>>>(hG, linAT, linA_b, linAf_w, linAf_b, finT, fin_b,
                                     finf_w, finf_b, outA, outF);

  // ---- GRU ----
  {
    dim3 g((3 * HH) / 64, (BB * LL) / 64);
    k_gemm<true, false><<<g, 256, 0, stream>>>(ig, HH, WihT, 3 * HH, bih, gi, 3 * HH,
                                               BB * LL, 3 * HH, HH);
  }
  k_gru<<<BB, 384, 0, stream>>>(gi, WhhT, bhh, hG, seq);

  // ---- node logits ----
  {
    dim3 g(HH / 64, (BB * LL) / 64);
    k_gemm<false, false><<<g, 256, 0, stream>>>(seq, HH, linN1T, HH, nullptr, part1, HH,
                                                BB * LL, HH, HH);
  }
  k_mgemm<0><<<(NN + 63) / 64, 256, 0, stream>>>(nodeEmb, HH, linN2bt, HH, nullptr,
                                                 (void*)part2, NN, HH);
  k_logits<<<NN / 4, 256, 0, stream>>>(part1, part2, linN_b, linNf_w, linNf_b, bs, logitsB);
  k_softmax<<<BB * LL, 64, 0, stream>>>(logitsB, bptr, bnodes, outNodes);
}

// Round 6
// 322.776 us; speedup vs baseline: 2.2395x; 2.2395x over previous
//
#include <hip/hip_runtime.h>
#include <math.h>

#define NN 12800
#define NE 204800
#define LL 24
#define HH 128
#define BB 64
#define RR 8
#define VAx 20
#define KC 1152  // R*H + H
#define CHK 8    // node chunks per batch for aggS
#define PS 16    // counter padding (ints per 64B line)

typedef __attribute__((ext_vector_type(8))) short bf16x8;
typedef __attribute__((ext_vector_type(4))) float f32x4;

__device__ inline unsigned short f2bf(float f) {
  unsigned u = __float_as_uint(f);
  unsigned r = u + 0x7FFF + ((u >> 16) & 1);  // RNE
  return (unsigned short)(r >> 16);
}
__device__ inline float bf2f(unsigned short s) {
  return __uint_as_float(((unsigned)s) << 16);
}
__device__ inline unsigned packbf(float lo, float hi) {
  return (unsigned)f2bf(lo) | ((unsigned)f2bf(hi) << 16);
}

// ---------------- mega prep: weight transforms + embed + padded-deg zero ----------------
__global__ void k_prep(const float* __restrict__ rgcnW, const float* __restrict__ rgcnRoot,
                       unsigned short* __restrict__ wcatT,
                       const float* __restrict__ linN_w, unsigned short* __restrict__ linN2bt,
                       const float* __restrict__ Wih, float* __restrict__ WihT,
                       const float* __restrict__ Whh, float* __restrict__ WhhT,
                       const float* __restrict__ linA_w, float* __restrict__ linAT,
                       const float* __restrict__ fin_w, float* __restrict__ finT,
                       float* __restrict__ linN1T,
                       const int* __restrict__ nt, const float* __restrict__ embN,
                       unsigned int* __restrict__ x, int* __restrict__ deg) {
  int idx = blockIdx.x * 256 + threadIdx.x;
  if (idx < HH * KC) {  // wcatT[d][k]
    int d = idx / KC, k = idx - d * KC;
    float v = (k < 1024) ? rgcnW[(k >> 7) * (HH * HH) + (k & 127) * HH + d]
                         : rgcnRoot[(k - 1024) * HH + d];
    wcatT[idx] = f2bf(v);
    return;
  }
  idx -= HH * KC;
  if (idx < HH * HH) {  // linN2bt[d][k] = linN_w[d][128+k]
    int d = idx >> 7, k = idx & 127;
    linN2bt[idx] = f2bf(linN_w[d * 2 * HH + HH + k]);
    return;
  }
  idx -= HH * HH;
  if (idx < 3 * HH * HH) {  // WihT[c*384+r] = Wih[r*128+c]
    int r = idx / HH, c = idx - r * HH;
    WihT[c * 384 + r] = Wih[r * HH + c];
    return;
  }
  idx -= 3 * HH * HH;
  if (idx < 3 * HH * HH) {  // WhhT
    int r = idx / HH, c = idx - r * HH;
    WhhT[c * 384 + r] = Whh[r * HH + c];
    return;
  }
  idx -= 3 * HH * HH;
  if (idx < HH * HH) {  // linAT
    int r = idx >> 7, c = idx & 127;
    linAT[c * HH + r] = linA_w[r * HH + c];
    return;
  }
  idx -= HH * HH;
  if (idx < HH * HH) {  // finT
    int r = idx >> 7, c = idx & 127;
    finT[c * HH + r] = fin_w[r * HH + c];
    return;
  }
  idx -= HH * HH;
  if (idx < HH * HH) {  // linN1T[c*128+r] = linN_w[r][c]
    int r = idx >> 7, c = idx & 127;
    linN1T[c * HH + r] = linN_w[r * 2 * HH + c];
    return;
  }
  idx -= HH * HH;
  if (idx < NN * 64) {  // embed -> bf16 pairs
    int n = idx >> 6, p = idx & 63;
    const float* e = embN + (size_t)nt[n] * HH + p * 2;
    x[idx] = packbf(e[0], e[1]);
    return;
  }
  idx -= NN * 64;
  if (idx < NN * PS) deg[idx] = 0;
}
#define PREP_TOTAL (HH * KC + HH * HH + 3 * HH * HH + 3 * HH * HH + HH * HH + HH * HH + HH * HH + NN * 64 + NN * PS)

// ---- batch CSR without atomics: bs is sorted, so boundary-detect + identity bnodes ----
__global__ void k_batchcsr(const int* __restrict__ bs, int* __restrict__ bptr,
                           int* __restrict__ bnodes) {
  int i = blockIdx.x * 256 + threadIdx.x;
  if (i >= NN) return;
  bnodes[i] = i;
  int b = bs[i];
  if (i == 0 || bs[i - 1] != b) bptr[b] = i;
  if (i == NN - 1) bptr[BB] = NN;
}

// ---- edge CSR with line-padded counters ----
__global__ void k_counte(const int* __restrict__ edst, int* __restrict__ deg) {
  int i = blockIdx.x * 256 + threadIdx.x;
  if (i < NE) atomicAdd(&deg[edst[i] * PS], 1);
}

// single-block scan over padded deg -> compact indptr + padded cur
__global__ __launch_bounds__(1024) void k_scane(const int* __restrict__ deg,
                                                int* __restrict__ indptr,
                                                int* __restrict__ cur) {
  __shared__ int ws[16];
  int tid = threadIdx.x;
  const int per = (NN + 1023) >> 10;
  int i0 = tid * per;
  int s = 0;
  for (int k = 0; k < per; ++k) {
    int i = i0 + k;
    if (i < NN) s += deg[i * PS];
  }
  int lane = tid & 63, wv = tid >> 6;
  int incl = s;
#pragma unroll
  for (int off = 1; off < 64; off <<= 1) {
    int t = __shfl_up(incl, off);
    if (lane >= off) incl += t;
  }
  if (lane == 63) ws[wv] = incl;
  __syncthreads();
  if (tid < 16) {
    int v = ws[tid];
    int inc = v;
#pragma unroll
    for (int off = 1; off < 16; off <<= 1) {
      int t = __shfl_up(inc, off);
      if (tid >= off) inc += t;
    }
    ws[tid] = inc - v;  // exclusive
  }
  __syncthreads();
  int run = ws[wv] + incl - s;
  for (int k = 0; k < per; ++k) {
    int i = i0 + k;
    if (i < NN) {
      indptr[i] = run;
      cur[i * PS] = run;
      run += deg[i * PS];
      if (i == NN - 1) indptr[NN] = run;
    }
  }
}

__global__ void k_scattere(const int* __restrict__ esrc, const int* __restrict__ edst,
                           const int* __restrict__ erel, int* __restrict__ cur,
                           int* __restrict__ esort) {
  int i = blockIdx.x * 256 + threadIdx.x;
  if (i >= NE) return;
  int p = atomicAdd(&cur[edst[i] * PS], 1);
  esort[p] = esrc[i] | (erel[i] << 16);
}

// ---------------- RGCN aggregation: one wave per node (bf16 x, bf16 A) ----------------
__global__ __launch_bounds__(256) void k_agg(const unsigned int* __restrict__ x,
                                             const int* __restrict__ indptr,
                                             const int* __restrict__ esort,
                                             unsigned int* __restrict__ A, int n0, int nc) {
  int wid = ((blockIdx.x * 256) + threadIdx.x) >> 6;
  int lane = threadIdx.x & 63;
  if (wid >= nc) return;
  int n = n0 + wid;
  float a0=0,a1=0,a2=0,a3=0,a4=0,a5=0,a6=0,a7=0;
  float b0=0,b1=0,b2=0,b3=0,b4=0,b5=0,b6=0,b7=0;
  int c0=0,c1=0,c2=0,c3=0,c4=0,c5=0,c6=0,c7=0;
  int e0 = indptr[n], e1 = indptr[n + 1];
  for (int e = e0; e < e1; ++e) {
    int pk = esort[e];
    int s = pk & 0xFFFF;
    int r = pk >> 16;
    unsigned v = x[s * 64 + lane];
    float v0 = bf2f((unsigned short)(v & 0xFFFF));
    float v1 = bf2f((unsigned short)(v >> 16));
    switch (r) {  // wave-uniform branch
      case 0: a0 += v0; b0 += v1; c0++; break;
      case 1: a1 += v0; b1 += v1; c1++; break;
      case 2: a2 += v0; b2 += v1; c2++; break;
      case 3: a3 += v0; b3 += v1; c3++; break;
      case 4: a4 += v0; b4 += v1; c4++; break;
      case 5: a5 += v0; b5 += v1; c5++; break;
      case 6: a6 += v0; b6 += v1; c6++; break;
      default: a7 += v0; b7 += v1; c7++; break;
    }
  }
  unsigned int* Ar = A + (size_t)wid * (KC / 2);
  float i0 = 1.0f / (float)(c0 > 0 ? c0 : 1);
  float i1 = 1.0f / (float)(c1 > 0 ? c1 : 1);
  float i2 = 1.0f / (float)(c2 > 0 ? c2 : 1);
  float i3 = 1.0f / (float)(c3 > 0 ? c3 : 1);
  float i4 = 1.0f / (float)(c4 > 0 ? c4 : 1);
  float i5 = 1.0f / (float)(c5 > 0 ? c5 : 1);
  float i6 = 1.0f / (float)(c6 > 0 ? c6 : 1);
  float i7 = 1.0f / (float)(c7 > 0 ? c7 : 1);
  Ar[0 * 64 + lane] = packbf(a0 * i0, b0 * i0);
  Ar[1 * 64 + lane] = packbf(a1 * i1, b1 * i1);
  Ar[2 * 64 + lane] = packbf(a2 * i2, b2 * i2);
  Ar[3 * 64 + lane] = packbf(a3 * i3, b3 * i3);
  Ar[4 * 64 + lane] = packbf(a4 * i4, b4 * i4);
  Ar[5 * 64 + lane] = packbf(a5 * i5, b5 * i5);
  Ar[6 * 64 + lane] = packbf(a6 * i6, b6 * i6);
  Ar[7 * 64 + lane] = packbf(a7 * i7, b7 * i7);
  Ar[512 + lane] = x[n * 64 + lane];  // root term
}

// ---------------- bf16 MFMA GEMM: C[M,128] = A[M,K](bf16) * B[K,128] ----------------
template <int OUTMODE>
__global__ __launch_bounds__(256) void k_mgemm(const unsigned short* __restrict__ Abf, int lda,
                                               const unsigned short* __restrict__ BTbf, int ldb,
                                               const float* __restrict__ bias,
                                               void* __restrict__ C, int M, int K) {
  __shared__ unsigned int ldsu[(8192 + 16384) / 4];
  char* ldsc = (char*)ldsu;
  int tid = threadIdx.x;
  int m0 = blockIdx.x * 64;
  int w = tid >> 6, l = tid & 63;
  int lrow = l & 15, lg = l >> 4;
  f32x4 acc[8] = {};

  const char* Ab = (const char*)Abf;
  const char* Bb = (const char*)BTbf;
  int KT = K >> 6;
  for (int kt = 0; kt < KT; ++kt) {
    int k0 = kt << 6;
#pragma unroll
    for (int i = 0; i < 2; ++i) {
      int slot = i * 256 + tid;
      int row = slot >> 3;
      int colb = (slot & 7) << 4;
      int gr = m0 + row;
      gr = gr < M ? gr : M - 1;
      size_t srcb = ((size_t)gr * lda + k0) * 2 + (size_t)(colb ^ ((row & 7) << 4));
      __builtin_amdgcn_global_load_lds((const unsigned int*)(Ab + srcb),
                                       (unsigned int*)(ldsc + slot * 16), 16, 0, 0);
    }
#pragma unroll
    for (int i = 0; i < 4; ++i) {
      int slot = i * 256 + tid;
      int row = slot >> 3;
      int colb = (slot & 7) << 4;
      size_t srcb = ((size_t)row * ldb + k0) * 2 + (size_t)(colb ^ ((row & 7) << 4));
      __builtin_amdgcn_global_load_lds((const unsigned int*)(Bb + srcb),
                                       (unsigned int*)(ldsc + 8192 + slot * 16), 16, 0, 0);
    }
    __syncthreads();
#pragma unroll
    for (int h = 0; h < 2; ++h) {
      int arow = w * 16 + lrow;
      bf16x8 af = *(const bf16x8*)(ldsc + arow * 128 +
                                   ((h * 64 + lg * 16) ^ ((arow & 7) << 4)));
#pragma unroll
      for (int c = 0; c < 8; ++c) {
        int brow = c * 16 + lrow;
        bf16x8 bf = *(const bf16x8*)(ldsc + 8192 + brow * 128 +
                                     ((h * 64 + lg * 16) ^ ((brow & 7) << 4)));
        acc[c] = __builtin_amdgcn_mfma_f32_16x16x32_bf16(af, bf, acc[c], 0, 0, 0);
      }
    }
    __syncthreads();
  }
#pragma unroll
  for (int c = 0; c < 8; ++c) {
#pragma unroll
    for (int r = 0; r < 4; ++r) {
      int gm = m0 + w * 16 + lg * 4 + r;
      if (gm >= M) continue;
      int gn = c * 16 + lrow;
      float v = acc[c][r];
      if (OUTMODE == 1) {
        v = fmaxf(v + bias[gn], 0.f);
        ((unsigned short*)C)[(size_t)gm * HH + gn] = f2bf(v);
      } else {
        ((float*)C)[(size_t)gm * HH + gn] = v;
      }
    }
  }
}

// ---------------- generic fp32 tiled GEMM (small GEMMs) ----------------
template <bool BIAS, bool RELU>
__global__ __launch_bounds__(256) void k_gemm(const float* __restrict__ Am, int lda,
                                              const float* __restrict__ Bm, int ldb,
                                              const float* __restrict__ bias,
                                              float* __restrict__ C, int ldc,
                                              int M, int Nc, int K) {
  __shared__ float As[16][65];
  __shared__ float Bs[16][65];
  int m0 = blockIdx.y * 64, n0 = blockIdx.x * 64;
  int tx = threadIdx.x & 15, ty = threadIdx.x >> 4;
  float acc[4][4] = {};
  for (int k0 = 0; k0 < K; k0 += 16) {
#pragma unroll
    for (int i = 0; i < 4; ++i) {
      int idx = threadIdx.x + i * 256;
      int kk = idx & 15, mm = idx >> 4;
      int gm = m0 + mm, gk = k0 + kk;
      As[kk][mm] = (gm < M && gk < K) ? Am[(size_t)gm * lda + gk] : 0.f;
    }
#pragma unroll
    for (int i = 0; i < 4; ++i) {
      int idx = threadIdx.x + i * 256;
      int nn = idx & 63, kk = idx >> 6;
      int gk = k0 + kk, gn = n0 + nn;
      Bs[kk][nn] = (gk < K && gn < Nc) ? Bm[(size_t)gk * ldb + gn] : 0.f;
    }
    __syncthreads();
#pragma unroll
    for (int kk = 0; kk < 16; ++kk) {
      float a[4], b[4];
#pragma unroll
      for (int i = 0; i < 4; ++i) a[i] = As[kk][ty * 4 + i];
#pragma unroll
      for (int j = 0; j < 4; ++j) b[j] = Bs[kk][tx * 4 + j];
#pragma unroll
      for (int i = 0; i < 4; ++i)
#pragma unroll
        for (int j = 0; j < 4; ++j) acc[i][j] = fmaf(a[i], b[j], acc[i][j]);
    }
    __syncthreads();
  }
#pragma unroll
  for (int i = 0; i < 4; ++i) {
    int gm = m0 + ty * 4 + i;
    if (gm >= M) continue;
#pragma unroll
    for (int j = 0; j < 4; ++j) {
      int gn = n0 + tx * 4 + j;
      if (gn >= Nc) continue;
      float v = acc[i][j];
      if (BIAS) v += bias[gn];
      if (RELU) v = fmaxf(v, 0.f);
      C[(size_t)gm * ldc + gn] = v;
    }
  }
}

// ---------------- aggS partials: 512 blocks (64 batches x 8 chunks) ----------------
__global__ __launch_bounds__(256) void k_aggS_part(const float* __restrict__ seqin,
                                                   const unsigned short* __restrict__ x,
                                                   const int* __restrict__ bptr,
                                                   const int* __restrict__ bnodes,
                                                   float* __restrict__ part) {
  int bc = blockIdx.x, b = bc >> 3, c = bc & 7;
  int h = threadIdx.x & 127, l0 = threadIdx.x >> 7;  // l0 in {0,1}
  int i0 = bptr[b], i1 = bptr[b + 1];
  int len = i1 - i0;
  int per = (len + CHK - 1) / CHK;
  int j0 = i0 + c * per;
  int j1 = j0 + per;
  if (j1 > i1) j1 = i1;
  float acc[12] = {};
  float esum = 0.f;
  for (int i = j0; i < j1; ++i) {
    int n = bnodes[i];
    float e = bf2f(x[n * HH + h]);
    esum += e;
    const float* srow = seqin + (size_t)n * LL;
#pragma unroll
    for (int t = 0; t < 12; ++t) acc[t] = fmaf(srow[l0 + 2 * t], e, acc[t]);
  }
  float* p = part + (size_t)bc * 25 * HH + h;
#pragma unroll
  for (int t = 0; t < 12; ++t) p[(l0 + 2 * t) * HH] = acc[t];
  if (l0 == 0) p[24 * HH] = esum;
}

// reduce partials; writes ig (with SOS at t=0) and hG
__global__ void k_aggS_red(const float* __restrict__ part, const int* __restrict__ bptr,
                           const float* __restrict__ embA, const int* __restrict__ act,
                           float* __restrict__ ig, float* __restrict__ hG) {
  int idx = blockIdx.x * 256 + threadIdx.x;
  if (idx >= BB * 25 * HH) return;
  int h = idx & 127;
  int rem = idx >> 7;
  int l = rem % 25, b = rem / 25;
  if (l == 23) {  // agg[23] is dropped by [:, :L]; reuse slot for ig[b][0] = SOS
    ig[((size_t)b * LL) * HH + h] = embA[(size_t)act[b] * HH + h];
    return;
  }
  float s = 0.f;
#pragma unroll
  for (int c = 0; c < CHK; ++c) s += part[(((size_t)(b * CHK + c)) * 25 + l) * HH + h];
  if (l == 24) {
    int len = bptr[b + 1] - bptr[b];
    hG[b * HH + h] = s / (float)len;
  } else {
    ig[((size_t)b * LL + l + 1) * HH + h] = s;
  }
}

// ---------------- merged heads ----------------
__global__ __launch_bounds__(128) void k_heads(const float* __restrict__ hG,
                                               const float* __restrict__ linAT,
                                               const float* __restrict__ linA_b,
                                               const float* __restrict__ linAf_w,
                                               const float* __restrict__ linAf_b,
                                               const float* __restrict__ finT,
                                               const float* __restrict__ fin_b,
                                               const float* __restrict__ finf_w,
                                               const float* __restrict__ finf_b,
                                               float* __restrict__ outA,
                                               float* __restrict__ outF) {
  int b = blockIdx.x >> 1, which = blockIdx.x & 1, j = threadIdx.x;
  __shared__ float hsh[HH], t1[HH];
  hsh[j] = hG[b * HH + j];
  __syncthreads();
  const float* Wt = which ? finT : linAT;
  const float* bb = which ? fin_b : linA_b;
  float s = bb[j];
  for (int k = 0; k < HH; ++k) s = fmaf(hsh[k], Wt[k * HH + j], s);
  t1[j] = fmaxf(s, 0.f);
  __syncthreads();
  if (which == 0) {
    if (j < VAx) {
      float o = linAf_b[j];
      for (int k = 0; k < HH; ++k) o = fmaf(t1[k], linAf_w[j * HH + k], o);
      outA[b * VAx + j] = o;
    }
  } else if (j == 0) {
    float o = finf_b[0];
    for (int k = 0; k < HH; ++k) o = fmaf(t1[k], finf_w[k], o);
    outF[b] = 1.f / (1.f + expf(-o));
  }
}

// ---------------- GRU: 64 blocks x 384 threads, Whh column in registers ----------------
__global__ __launch_bounds__(384) void k_gru(const float* __restrict__ gi,
                                             const float* __restrict__ WhhT,  // [128][384]
                                             const float* __restrict__ bhh,
                                             const float* __restrict__ hG,
                                             float* __restrict__ seqout) {
  int b = blockIdx.x, tid = threadIdx.x;
  int gate = tid >> 7, j = tid & 127;
  __shared__ float h[HH];
  __shared__ float sz[HH], sg[HH];
  float w[HH];
#pragma unroll
  for (int k = 0; k < HH; ++k) w[k] = WhhT[k * 384 + tid];
  float bh = bhh[tid];
  if (tid < HH) h[tid] = hG[b * HH + tid];
  __syncthreads();
  const float* gib = gi + (size_t)b * LL * 384;
  for (int t = 0; t < LL; ++t) {
    float giv = gib[t * 384 + tid];
    float gin = (gate == 0) ? gib[t * 384 + 256 + j] : 0.f;  // wave-uniform branch
    float hj = h[j];
    float g0 = 0.f, g1 = 0.f, g2 = 0.f, g3 = 0.f;
    const float4* h4 = (const float4*)h;
#pragma unroll
    for (int k4 = 0; k4 < HH / 4; ++k4) {
      float4 hv = h4[k4];
      g0 = fmaf(w[4 * k4 + 0], hv.x, g0);
      g1 = fmaf(w[4 * k4 + 1], hv.y, g1);
      g2 = fmaf(w[4 * k4 + 2], hv.z, g2);
      g3 = fmaf(w[4 * k4 + 3], hv.w, g3);
    }
    float g = bh + ((g0 + g1) + (g2 + g3));
    float r = 0.f;
    if (gate == 0) {
      r = 1.f / (1.f + expf(-(giv + g)));
    } else if (gate == 1) {
      sz[j] = 1.f / (1.f + expf(-(giv + g)));
    } else {
      sg[j] = g;
    }
    __syncthreads();
    if (gate == 0) {
      float n = tanhf(gin + r * sg[j]);
      float z = sz[j];
      float hn = (1.f - z) * n + z * hj;
      h[j] = hn;
      seqout[((size_t)b * LL + t) * HH + j] = hn;
    }
    __syncthreads();
  }
}

// ---------------- fused logits ----------------
__global__ __launch_bounds__(256) void k_logits(const float* __restrict__ part1,
                                                const float* __restrict__ part2,
                                                const float* __restrict__ linN_b,
                                                const float* __restrict__ linNf_w,
                                                const float* __restrict__ linNf_b,
                                                const int* __restrict__ bs,
                                                float* __restrict__ logits) {
  int wid = ((blockIdx.x * 256) + threadIdx.x) >> 6;
  int lane = threadIdx.x & 63;
  if (wid >= NN) return;
  int n = wid;
  int b = bs[n];
  float p2a = part2[n * HH + lane] + linN_b[lane];
  float p2b = part2[n * HH + 64 + lane] + linN_b[64 + lane];
  float wa = linNf_w[lane], wb = linNf_w[64 + lane];
  const float* p1 = part1 + (size_t)b * LL * HH;
  float bf = linNf_b[0];
  for (int l = 0; l < LL; ++l) {
    float v = fmaxf(p1[l * HH + lane] + p2a, 0.f) * wa +
              fmaxf(p1[l * HH + 64 + lane] + p2b, 0.f) * wb;
#pragma unroll
    for (int off = 32; off > 0; off >>= 1) v += __shfl_down(v, off);
    if (lane == 0) logits[n * LL + l] = v + bf;
  }
}

// ---------------- segment softmax ----------------
__global__ __launch_bounds__(64) void k_softmax(const float* __restrict__ logits,
                                                const int* __restrict__ bptr,
                                                const int* __restrict__ bnodes,
                                                float* __restrict__ outN) {
  int b = blockIdx.x / LL, l = blockIdx.x % LL;
  int lane = threadIdx.x;
  int i0 = bptr[b], i1 = bptr[b + 1];
  float m = -1e30f;
  for (int i = i0 + lane; i < i1; i += 64) m = fmaxf(m, logits[bnodes[i] * LL + l]);
#pragma unroll
  for (int off = 32; off > 0; off >>= 1) m = fmaxf(m, __shfl_xor(m, off));
  float s = 0.f;
  for (int i = i0 + lane; i < i1; i += 64) s += expf(logits[bnodes[i] * LL + l] - m);
#pragma unroll
  for (int off = 32; off > 0; off >>= 1) s += __shfl_xor(s, off);
  float inv = 1.f / s;
  for (int i = i0 + lane; i < i1; i += 64) {
    int n = bnodes[i];
    outN[n * LL + l] = expf(logits[n * LL + l] - m) * inv;
  }
}

// ---------------- host ----------------
extern "C" void kernel_launch(void* const* d_in, const int* in_sizes, int n_in,
                              void* d_out, int out_size, void* d_ws, size_t ws_size,
                              hipStream_t stream) {
  const int* nodeTypes = (const int*)d_in[0];
  const int* esrc = (const int*)d_in[1];
  const int* edst = esrc + NE;
  const int* erel = (const int*)d_in[2];
  const int* bs = (const int*)d_in[3];
  const float* seqin = (const float*)d_in[4];
  const int* actin = (const int*)d_in[7];
  const float* embN = (const float*)d_in[8];
  const float* embA = (const float*)d_in[9];
  const float* rgcnW = (const float*)d_in[10];
  const float* rgcnRoot = (const float*)d_in[11];
  const float* rgcnB = (const float*)d_in[12];
  const float* Wih = (const float*)d_in[13];
  const float* Whh = (const float*)d_in[14];
  const float* bih = (const float*)d_in[15];
  const float* bhh = (const float*)d_in[16];
  const float* linA_w = (const float*)d_in[17];
  const float* linA_b = (const float*)d_in[18];
  const float* linAf_w = (const float*)d_in[19];
  const float* linAf_b = (const float*)d_in[20];
  const float* linN_w = (const float*)d_in[21];
  const float* linN_b = (const float*)d_in[22];
  const float* linNf_w = (const float*)d_in[23];
  const float* linNf_b = (const float*)d_in[24];
  const float* fin_w = (const float*)d_in[25];
  const float* fin_b = (const float*)d_in[26];
  const float* finf_w = (const float*)d_in[27];
  const float* finf_b = (const float*)d_in[28];

  float* outA = (float*)d_out;
  float* outNodes = outA + BB * VAx;
  float* outF = outNodes + (size_t)NN * LL;

  char* basep = (char*)d_ws;
  size_t off = 0;
  auto alloc = [&](size_t bytes) -> void* {
    void* p = basep + off;
    off = (off + bytes + 255) & ~(size_t)255;
    return p;
  };

  unsigned int* x = (unsigned int*)alloc(sizeof(unsigned int) * NN * 64);   // bf16 pairs
  unsigned int* x2 = (unsigned int*)alloc(sizeof(unsigned int) * NN * 64);  // bf16 pairs
  float* hG = (float*)alloc(sizeof(float) * BB * HH);
  unsigned short* wcatT = (unsigned short*)alloc(sizeof(unsigned short) * HH * KC);
  unsigned short* linN2bt = (unsigned short*)alloc(sizeof(unsigned short) * HH * HH);
  float* WihT = (float*)alloc(sizeof(float) * HH * 3 * HH);
  float* WhhT = (float*)alloc(sizeof(float) * HH * 3 * HH);
  float* linAT = (float*)alloc(sizeof(float) * HH * HH);
  float* finT = (float*)alloc(sizeof(float) * HH * HH);
  float* linN1T = (float*)alloc(sizeof(float) * HH * HH);
  float* part = (float*)alloc(sizeof(float) * BB * CHK * 25 * HH);
  float* ig = (float*)alloc(sizeof(float) * BB * LL * HH);
  float* gi = (float*)alloc(sizeof(float) * BB * LL * 3 * HH);
  float* seq = (float*)alloc(sizeof(float) * BB * LL * HH);
  float* part1 = (float*)alloc(sizeof(float) * BB * LL * HH);
  float* part2 = (float*)alloc(sizeof(float) * NN * HH);
  float* logitsB = (float*)alloc(sizeof(float) * NN * LL);
  int* deg = (int*)alloc(sizeof(int) * NN * PS);
  int* cur = (int*)alloc(sizeof(int) * NN * PS);
  int* indptr = (int*)alloc(sizeof(int) * (NN + 1));
  int* esort = (int*)alloc(sizeof(int) * NE);
  int* bptr = (int*)alloc(sizeof(int) * (BB + 1));
  int* bnodes = (int*)alloc(sizeof(int) * NN);

  size_t remain = (ws_size > off) ? (ws_size - off) : 0;
  int NCk = NN;
  while ((size_t)NCk * KC * 2 > remain && NCk > 100) NCk >>= 1;
  unsigned int* A = (unsigned int*)alloc((size_t)NCk * (KC / 2) * sizeof(unsigned int));

  // ---- prep (1 launch): weight transforms, embed, zero padded deg ----
  k_prep<<<(PREP_TOTAL + 255) / 256, 256, 0, stream>>>(
      rgcnW, rgcnRoot, wcatT, linN_w, linN2bt, Wih, WihT, Whh, WhhT, linA_w, linAT,
      fin_w, finT, linN1T, nodeTypes, embN, x, deg);

  // ---- batch CSR (no atomics; bs sorted) + edge CSR (padded counters) ----
  k_batchcsr<<<(NN + 255) / 256, 256, 0, stream>>>(bs, bptr, bnodes);
  k_counte<<<(NE + 255) / 256, 256, 0, stream>>>(edst, deg);
  k_scane<<<1, 1024, 0, stream>>>(deg, indptr, cur);
  k_scattere<<<(NE + 255) / 256, 256, 0, stream>>>(esrc, edst, erel, cur, esort);

  // ---- 2 RGCN layers (shared weights), bf16 MFMA ----
  const unsigned int* xin = x;
  unsigned int* xout = x2;
  for (int layer = 0; layer < 2; ++layer) {
    for (int n0 = 0; n0 < NN; n0 += NCk) {
      int nc = NN - n0 < NCk ? NN - n0 : NCk;
      k_agg<<<(nc + 3) / 4, 256, 0, stream>>>(xin, indptr, esort, A, n0, nc);
      k_mgemm<1><<<(nc + 63) / 64, 256, 0, stream>>>(
          (const unsigned short*)A, KC, wcatT, KC, rgcnB,
          (void*)((unsigned short*)xout + (size_t)n0 * HH), nc, KC);
    }
    const unsigned int* t = xin;
    xin = xout;
    xout = (unsigned int*)t;
  }
  const unsigned short* nodeEmb = (const unsigned short*)xin;

  // ---- aggS partial/reduce: produces ig (with SOS) and hG ----
  k_aggS_part<<<BB * CHK, 256, 0, stream>>>(seqin, nodeEmb, bptr, bnodes, part);
  k_aggS_red<<<(BB * 25 * HH + 255) / 256, 256, 0, stream>>>(part, bptr, embA, actin, ig, hG);

  // ---- heads ----
  k_heads<<<2 * BB, HH, 0, stream>>>(hG, linAT, linA_b, linAf_w, linAf_b, finT, fin_b,
                                     finf_w, finf_b, outA, outF);

  // ---- GRU ----
  {
    dim3 g((3 * HH) / 64, (BB * LL) / 64);
    k_gemm<true, false><<<g, 256, 0, stream>>>(ig, HH, WihT, 3 * HH, bih, gi, 3 * HH,
                                               BB * LL, 3 * HH, HH);
  }
  k_gru<<<BB, 384, 0, stream>>>(gi, WhhT, bhh, hG, seq);

  // ---- node logits ----
  {
    dim3 g(HH / 64, (BB * LL) / 64);
    k_gemm<false, false><<<g, 256, 0, stream>>>(seq, HH, linN1T, HH, nullptr, part1, HH,
                                                BB * LL, HH, HH);
  }
  k_mgemm<0><<<(NN + 63) / 64, 256, 0, stream>>>(nodeEmb, HH, linN2bt, HH, nullptr,
                                                 (void*)part2, NN, HH);
  k_logits<<<NN / 4, 256, 0, stream>>>(part1, part2, linN_b, linNf_w, linNf_b, bs, logitsB);
  k_softmax<<<BB * LL, 64, 0, stream>>>(logitsB, bptr, bnodes, outNodes);
}

// Round 7
// 264.959 us; speedup vs baseline: 2.7281x; 1.2182x over previous
//
#include <hip/hip_runtime.h>
#include <math.h>

#define NN 12800
#define NE 204800
#define LL 24
#define HH 128
#define BB 64
#define RR 8
#define VAx 20
#define KC 1152  // R*H + H
#define CHK 8    // node chunks per batch for aggS
#define PS 16    // counter padding (ints per 64B line)

typedef __attribute__((ext_vector_type(8))) short bf16x8;
typedef __attribute__((ext_vector_type(4))) float f32x4;

__device__ inline unsigned short f2bf(float f) {
  unsigned u = __float_as_uint(f);
  unsigned r = u + 0x7FFF + ((u >> 16) & 1);  // RNE
  return (unsigned short)(r >> 16);
}
__device__ inline float bf2f(unsigned short s) {
  return __uint_as_float(((unsigned)s) << 16);
}
__device__ inline unsigned packbf(float lo, float hi) {
  return (unsigned)f2bf(lo) | ((unsigned)f2bf(hi) << 16);
}

// ---------------- mega prep: weight transforms + embed + padded-deg zero ----------------
__global__ void k_prep(const float* __restrict__ rgcnW, const float* __restrict__ rgcnRoot,
                       unsigned short* __restrict__ wcatT,
                       const float* __restrict__ linN_w, unsigned short* __restrict__ linN2bt,
                       const float* __restrict__ Wih, unsigned short* __restrict__ Wihbt,
                       const float* __restrict__ Whh, float* __restrict__ WhhT,
                       const float* __restrict__ linA_w, float* __restrict__ linAT,
                       const float* __restrict__ fin_w, float* __restrict__ finT,
                       unsigned short* __restrict__ linN1bt,
                       const int* __restrict__ nt, const float* __restrict__ embN,
                       unsigned int* __restrict__ x, int* __restrict__ deg) {
  int idx = blockIdx.x * 256 + threadIdx.x;
  if (idx < HH * KC) {  // wcatT[d][k]
    int d = idx / KC, k = idx - d * KC;
    float v = (k < 1024) ? rgcnW[(k >> 7) * (HH * HH) + (k & 127) * HH + d]
                         : rgcnRoot[(k - 1024) * HH + d];
    wcatT[idx] = f2bf(v);
    return;
  }
  idx -= HH * KC;
  if (idx < HH * HH) {  // linN2bt[d][k] = linN_w[d][128+k]
    int d = idx >> 7, k = idx & 127;
    linN2bt[idx] = f2bf(linN_w[d * 2 * HH + HH + k]);
    return;
  }
  idx -= HH * HH;
  if (idx < 3 * HH * HH) {  // Wihbt = bf16(Wih), already [384][128] B-layout
    Wihbt[idx] = f2bf(Wih[idx]);
    return;
  }
  idx -= 3 * HH * HH;
  if (idx < 3 * HH * HH) {  // WhhT (fp32 transpose for GRU)
    int r = idx / HH, c = idx - r * HH;
    WhhT[c * 384 + r] = Whh[r * HH + c];
    return;
  }
  idx -= 3 * HH * HH;
  if (idx < HH * HH) {  // linAT
    int r = idx >> 7, c = idx & 127;
    linAT[c * HH + r] = linA_w[r * HH + c];
    return;
  }
  idx -= HH * HH;
  if (idx < HH * HH) {  // finT
    int r = idx >> 7, c = idx & 127;
    finT[c * HH + r] = fin_w[r * HH + c];
    return;
  }
  idx -= HH * HH;
  if (idx < HH * HH) {  // linN1bt[o][k] = bf16(linN_w[o][k])
    int o = idx >> 7, k = idx & 127;
    linN1bt[idx] = f2bf(linN_w[o * 2 * HH + k]);
    return;
  }
  idx -= HH * HH;
  if (idx < NN * 64) {  // embed -> bf16 pairs
    int n = idx >> 6, p = idx & 63;
    const float* e = embN + (size_t)nt[n] * HH + p * 2;
    x[idx] = packbf(e[0], e[1]);
    return;
  }
  idx -= NN * 64;
  if (idx < NN * PS) deg[idx] = 0;
}
#define PREP_TOTAL (HH * KC + HH * HH + 3 * HH * HH + 3 * HH * HH + HH * HH + HH * HH + HH * HH + NN * 64 + NN * PS)

// ---- fused: edge-degree count (padded counters) + batch boundary detect ----
__global__ void k_count(const int* __restrict__ edst, int* __restrict__ deg,
                        const int* __restrict__ bs, int* __restrict__ bptr) {
  int i = blockIdx.x * 256 + threadIdx.x;
  if (i < NE) atomicAdd(&deg[edst[i] * PS], 1);
  if (i < NN) {  // bs sorted -> boundary detection
    int b = bs[i];
    if (i == 0 || bs[i - 1] != b) bptr[b] = i;
    if (i == NN - 1) bptr[BB] = NN;
  }
}

// single-block scan over padded deg -> compact indptr + padded cur
__global__ __launch_bounds__(1024) void k_scane(const int* __restrict__ deg,
                                                int* __restrict__ indptr,
                                                int* __restrict__ cur) {
  __shared__ int ws[16];
  int tid = threadIdx.x;
  const int per = (NN + 1023) >> 10;
  int i0 = tid * per;
  int s = 0;
  for (int k = 0; k < per; ++k) {
    int i = i0 + k;
    if (i < NN) s += deg[i * PS];
  }
  int lane = tid & 63, wv = tid >> 6;
  int incl = s;
#pragma unroll
  for (int off = 1; off < 64; off <<= 1) {
    int t = __shfl_up(incl, off);
    if (lane >= off) incl += t;
  }
  if (lane == 63) ws[wv] = incl;
  __syncthreads();
  if (tid < 16) {
    int v = ws[tid];
    int inc = v;
#pragma unroll
    for (int off = 1; off < 16; off <<= 1) {
      int t = __shfl_up(inc, off);
      if (tid >= off) inc += t;
    }
    ws[tid] = inc - v;  // exclusive
  }
  __syncthreads();
  int run = ws[wv] + incl - s;
  for (int k = 0; k < per; ++k) {
    int i = i0 + k;
    if (i < NN) {
      indptr[i] = run;
      cur[i * PS] = run;
      run += deg[i * PS];
      if (i == NN - 1) indptr[NN] = run;
    }
  }
}

__global__ void k_scattere(const int* __restrict__ esrc, const int* __restrict__ edst,
                           const int* __restrict__ erel, int* __restrict__ cur,
                           int* __restrict__ esort) {
  int i = blockIdx.x * 256 + threadIdx.x;
  if (i >= NE) return;
  int p = atomicAdd(&cur[edst[i] * PS], 1);
  esort[p] = esrc[i] | (erel[i] << 16);
}

// ---------------- RGCN aggregation: one wave per node, 4x unrolled gather ----------------
__global__ __launch_bounds__(256) void k_agg(const unsigned int* __restrict__ x,
                                             const int* __restrict__ indptr,
                                             const int* __restrict__ esort,
                                             unsigned int* __restrict__ A, int n0, int nc) {
  int wid = ((blockIdx.x * 256) + threadIdx.x) >> 6;
  int lane = threadIdx.x & 63;
  if (wid >= nc) return;
  int n = n0 + wid;
  float a0=0,a1=0,a2=0,a3=0,a4=0,a5=0,a6=0,a7=0;
  float b0=0,b1=0,b2=0,b3=0,b4=0,b5=0,b6=0,b7=0;
  int c0=0,c1=0,c2=0,c3=0,c4=0,c5=0,c6=0,c7=0;
  int e0 = indptr[n], e1 = indptr[n + 1];

#define ACCV(RV, VV)                                                              \
  {                                                                               \
    float v0_ = bf2f((unsigned short)((VV) & 0xFFFF));                            \
    float v1_ = bf2f((unsigned short)((VV) >> 16));                               \
    switch (RV) {                                                                 \
      case 0: a0 += v0_; b0 += v1_; c0++; break;                                  \
      case 1: a1 += v0_; b1 += v1_; c1++; break;                                  \
      case 2: a2 += v0_; b2 += v1_; c2++; break;                                  \
      case 3: a3 += v0_; b3 += v1_; c3++; break;                                  \
      case 4: a4 += v0_; b4 += v1_; c4++; break;                                  \
      case 5: a5 += v0_; b5 += v1_; c5++; break;                                  \
      case 6: a6 += v0_; b6 += v1_; c6++; break;                                  \
      default: a7 += v0_; b7 += v1_; c7++; break;                                 \
    }                                                                             \
  }

  int e = e0;
  for (; e + 4 <= e1; e += 4) {  // 4 independent gather chains in flight
    int pk0 = esort[e], pk1 = esort[e + 1], pk2 = esort[e + 2], pk3 = esort[e + 3];
    unsigned v0 = x[(size_t)(pk0 & 0xFFFF) * 64 + lane];
    unsigned v1 = x[(size_t)(pk1 & 0xFFFF) * 64 + lane];
    unsigned v2 = x[(size_t)(pk2 & 0xFFFF) * 64 + lane];
    unsigned v3 = x[(size_t)(pk3 & 0xFFFF) * 64 + lane];
    ACCV(pk0 >> 16, v0);
    ACCV(pk1 >> 16, v1);
    ACCV(pk2 >> 16, v2);
    ACCV(pk3 >> 16, v3);
  }
  for (; e < e1; ++e) {
    int pk = esort[e];
    unsigned v = x[(size_t)(pk & 0xFFFF) * 64 + lane];
    ACCV(pk >> 16, v);
  }
#undef ACCV

  unsigned int* Ar = A + (size_t)wid * (KC / 2);
  float i0 = 1.0f / (float)(c0 > 0 ? c0 : 1);
  float i1 = 1.0f / (float)(c1 > 0 ? c1 : 1);
  float i2 = 1.0f / (float)(c2 > 0 ? c2 : 1);
  float i3 = 1.0f / (float)(c3 > 0 ? c3 : 1);
  float i4 = 1.0f / (float)(c4 > 0 ? c4 : 1);
  float i5 = 1.0f / (float)(c5 > 0 ? c5 : 1);
  float i6 = 1.0f / (float)(c6 > 0 ? c6 : 1);
  float i7 = 1.0f / (float)(c7 > 0 ? c7 : 1);
  Ar[0 * 64 + lane] = packbf(a0 * i0, b0 * i0);
  Ar[1 * 64 + lane] = packbf(a1 * i1, b1 * i1);
  Ar[2 * 64 + lane] = packbf(a2 * i2, b2 * i2);
  Ar[3 * 64 + lane] = packbf(a3 * i3, b3 * i3);
  Ar[4 * 64 + lane] = packbf(a4 * i4, b4 * i4);
  Ar[5 * 64 + lane] = packbf(a5 * i5, b5 * i5);
  Ar[6 * 64 + lane] = packbf(a6 * i6, b6 * i6);
  Ar[7 * 64 + lane] = packbf(a7 * i7, b7 * i7);
  Ar[512 + lane] = x[n * 64 + lane];  // root term
}

// ---------------- bf16 MFMA GEMM: C[M, Nc] = A[M,K](bf16) * BT[Nc,K]^T ----------------
// 64-row tile, 128-col chunk via blockIdx.y. OUTMODE: 0 = fp32 store;
// 1 = bias+relu, bf16 store; 2 = bias, fp32 store.
template <int OUTMODE>
__global__ __launch_bounds__(256) void k_mgemm(const unsigned short* __restrict__ Abf, int lda,
                                               const unsigned short* __restrict__ BTbf, int ldb,
                                               const float* __restrict__ bias,
                                               void* __restrict__ C, int ldc, int M, int K) {
  __shared__ unsigned int ldsu[(8192 + 16384) / 4];
  char* ldsc = (char*)ldsu;
  int tid = threadIdx.x;
  int m0 = blockIdx.x * 64;
  int n0c = blockIdx.y * 128;
  int w = tid >> 6, l = tid & 63;
  int lrow = l & 15, lg = l >> 4;
  f32x4 acc[8] = {};

  const char* Ab = (const char*)Abf;
  const char* Bb = (const char*)(BTbf + (size_t)n0c * ldb);
  int KT = K >> 6;
  for (int kt = 0; kt < KT; ++kt) {
    int k0 = kt << 6;
#pragma unroll
    for (int i = 0; i < 2; ++i) {
      int slot = i * 256 + tid;
      int row = slot >> 3;
      int colb = (slot & 7) << 4;
      int gr = m0 + row;
      gr = gr < M ? gr : M - 1;
      size_t srcb = ((size_t)gr * lda + k0) * 2 + (size_t)(colb ^ ((row & 7) << 4));
      __builtin_amdgcn_global_load_lds((const unsigned int*)(Ab + srcb),
                                       (unsigned int*)(ldsc + slot * 16), 16, 0, 0);
    }
#pragma unroll
    for (int i = 0; i < 4; ++i) {
      int slot = i * 256 + tid;
      int row = slot >> 3;
      int colb = (slot & 7) << 4;
      size_t srcb = ((size_t)row * ldb + k0) * 2 + (size_t)(colb ^ ((row & 7) << 4));
      __builtin_amdgcn_global_load_lds((const unsigned int*)(Bb + srcb),
                                       (unsigned int*)(ldsc + 8192 + slot * 16), 16, 0, 0);
    }
    __syncthreads();
#pragma unroll
    for (int h = 0; h < 2; ++h) {
      int arow = w * 16 + lrow;
      bf16x8 af = *(const bf16x8*)(ldsc + arow * 128 +
                                   ((h * 64 + lg * 16) ^ ((arow & 7) << 4)));
#pragma unroll
      for (int c = 0; c < 8; ++c) {
        int brow = c * 16 + lrow;
        bf16x8 bf = *(const bf16x8*)(ldsc + 8192 + brow * 128 +
                                     ((h * 64 + lg * 16) ^ ((brow & 7) << 4)));
        acc[c] = __builtin_amdgcn_mfma_f32_16x16x32_bf16(af, bf, acc[c], 0, 0, 0);
      }
    }
    __syncthreads();
  }
#pragma unroll
  for (int c = 0; c < 8; ++c) {
#pragma unroll
    for (int r = 0; r < 4; ++r) {
      int gm = m0 + w * 16 + lg * 4 + r;
      if (gm >= M) continue;
      int gn = n0c + c * 16 + lrow;
      float v = acc[c][r];
      if (OUTMODE == 1) {
        v = fmaxf(v + bias[gn], 0.f);
        ((unsigned short*)C)[(size_t)gm * ldc + gn] = f2bf(v);
      } else if (OUTMODE == 2) {
        ((float*)C)[(size_t)gm * ldc + gn] = v + bias[gn];
      } else {
        ((float*)C)[(size_t)gm * ldc + gn] = v;
      }
    }
  }
}

// ---------------- aggS partials: 512 blocks (64 batches x 8 chunks) ----------------
__global__ __launch_bounds__(256) void k_aggS_part(const float* __restrict__ seqin,
                                                   const unsigned short* __restrict__ x,
                                                   const int* __restrict__ bptr,
                                                   float* __restrict__ part) {
  int bc = blockIdx.x, b = bc >> 3, c = bc & 7;
  int h = threadIdx.x & 127, l0 = threadIdx.x >> 7;  // l0 in {0,1}
  int i0 = bptr[b], i1 = bptr[b + 1];
  int len = i1 - i0;
  int per = (len + CHK - 1) / CHK;
  int j0 = i0 + c * per;
  int j1 = j0 + per;
  if (j1 > i1) j1 = i1;
  float acc[12] = {};
  float esum = 0.f;
  for (int n = j0; n < j1; ++n) {  // bnodes == identity (bs sorted)
    float e = bf2f(x[n * HH + h]);
    esum += e;
    const float* srow = seqin + (size_t)n * LL;
#pragma unroll
    for (int t = 0; t < 12; ++t) acc[t] = fmaf(srow[l0 + 2 * t], e, acc[t]);
  }
  float* p = part + (size_t)bc * 25 * HH + h;
#pragma unroll
  for (int t = 0; t < 12; ++t) p[(l0 + 2 * t) * HH] = acc[t];
  if (l0 == 0) p[24 * HH] = esum;
}

// reduce partials; writes ig (bf16, with SOS at t=0) and hG (fp32)
__global__ void k_aggS_red(const float* __restrict__ part, const int* __restrict__ bptr,
                           const float* __restrict__ embA, const int* __restrict__ act,
                           unsigned short* __restrict__ ig, float* __restrict__ hG) {
  int idx = blockIdx.x * 256 + threadIdx.x;
  if (idx >= BB * 25 * HH) return;
  int h = idx & 127;
  int rem = idx >> 7;
  int l = rem % 25, b = rem / 25;
  if (l == 23) {  // agg[23] dropped by [:, :L]; reuse slot for ig[b][0] = SOS
    ig[((size_t)b * LL) * HH + h] = f2bf(embA[(size_t)act[b] * HH + h]);
    return;
  }
  float s = 0.f;
#pragma unroll
  for (int c = 0; c < CHK; ++c) s += part[(((size_t)(b * CHK + c)) * 25 + l) * HH + h];
  if (l == 24) {
    int len = bptr[b + 1] - bptr[b];
    hG[b * HH + h] = s / (float)len;
  } else {
    ig[((size_t)b * LL + l + 1) * HH + h] = f2bf(s);
  }
}

// ---------------- merged heads ----------------
__global__ __launch_bounds__(128) void k_heads(const float* __restrict__ hG,
                                               const float* __restrict__ linAT,
                                               const float* __restrict__ linA_b,
                                               const float* __restrict__ linAf_w,
                                               const float* __restrict__ linAf_b,
                                               const float* __restrict__ finT,
                                               const float* __restrict__ fin_b,
                                               const float* __restrict__ finf_w,
                                               const float* __restrict__ finf_b,
                                               float* __restrict__ outA,
                                               float* __restrict__ outF) {
  int b = blockIdx.x >> 1, which = blockIdx.x & 1, j = threadIdx.x;
  __shared__ float hsh[HH], t1[HH];
  hsh[j] = hG[b * HH + j];
  __syncthreads();
  const float* Wt = which ? finT : linAT;
  const float* bb = which ? fin_b : linA_b;
  float s = bb[j];
  for (int k = 0; k < HH; ++k) s = fmaf(hsh[k], Wt[k * HH + j], s);
  t1[j] = fmaxf(s, 0.f);
  __syncthreads();
  if (which == 0) {
    if (j < VAx) {
      float o = linAf_b[j];
      for (int k = 0; k < HH; ++k) o = fmaf(t1[k], linAf_w[j * HH + k], o);
      outA[b * VAx + j] = o;
    }
  } else if (j == 0) {
    float o = finf_b[0];
    for (int k = 0; k < HH; ++k) o = fmaf(t1[k], finf_w[k], o);
    outF[b] = 1.f / (1.f + expf(-o));
  }
}

// ---------------- GRU: 64 blocks x 384 threads, Whh column in registers ----------------
__global__ __launch_bounds__(384) void k_gru(const float* __restrict__ gi,
                                             const float* __restrict__ WhhT,  // [128][384]
                                             const float* __restrict__ bhh,
                                             const float* __restrict__ hG,
                                             unsigned short* __restrict__ seqout) {
  int b = blockIdx.x, tid = threadIdx.x;
  int gate = tid >> 7, j = tid & 127;
  __shared__ float h[HH];
  __shared__ float sz[HH], sg[HH];
  float w[HH];
#pragma unroll
  for (int k = 0; k < HH; ++k) w[k] = WhhT[k * 384 + tid];
  float bh = bhh[tid];
  if (tid < HH) h[tid] = hG[b * HH + tid];
  __syncthreads();
  const float* gib = gi + (size_t)b * LL * 384;
  for (int t = 0; t < LL; ++t) {
    float giv = gib[t * 384 + tid];
    float gin = (gate == 0) ? gib[t * 384 + 256 + j] : 0.f;  // wave-uniform branch
    float hj = h[j];
    float g0 = 0.f, g1 = 0.f, g2 = 0.f, g3 = 0.f;
    const float4* h4 = (const float4*)h;
#pragma unroll
    for (int k4 = 0; k4 < HH / 4; ++k4) {
      float4 hv = h4[k4];
      g0 = fmaf(w[4 * k4 + 0], hv.x, g0);
      g1 = fmaf(w[4 * k4 + 1], hv.y, g1);
      g2 = fmaf(w[4 * k4 + 2], hv.z, g2);
      g3 = fmaf(w[4 * k4 + 3], hv.w, g3);
    }
    float g = bh + ((g0 + g1) + (g2 + g3));
    float r = 0.f;
    if (gate == 0) {
      r = 1.f / (1.f + expf(-(giv + g)));
    } else if (gate == 1) {
      sz[j] = 1.f / (1.f + expf(-(giv + g)));
    } else {
      sg[j] = g;
    }
    __syncthreads();
    if (gate == 0) {
      float n = tanhf(gin + r * sg[j]);
      float z = sz[j];
      float hn = (1.f - z) * n + z * hj;
      h[j] = hn;
      seqout[((size_t)b * LL + t) * HH + j] = f2bf(hn);
    }
    __syncthreads();
  }
}

// ---------------- fused logits ----------------
__global__ __launch_bounds__(256) void k_logits(const float* __restrict__ part1,
                                                const float* __restrict__ part2,
                                                const float* __restrict__ linN_b,
                                                const float* __restrict__ linNf_w,
                                                const float* __restrict__ linNf_b,
                                                const int* __restrict__ bs,
                                                float* __restrict__ logits) {
  int wid = ((blockIdx.x * 256) + threadIdx.x) >> 6;
  int lane = threadIdx.x & 63;
  if (wid >= NN) return;
  int n = wid;
  int b = bs[n];
  float p2a = part2[n * HH + lane] + linN_b[lane];
  float p2b = part2[n * HH + 64 + lane] + linN_b[64 + lane];
  float wa = linNf_w[lane], wb = linNf_w[64 + lane];
  const float* p1 = part1 + (size_t)b * LL * HH;
  float bf = linNf_b[0];
  for (int l = 0; l < LL; ++l) {
    float v = fmaxf(p1[l * HH + lane] + p2a, 0.f) * wa +
              fmaxf(p1[l * HH + 64 + lane] + p2b, 0.f) * wb;
#pragma unroll
    for (int off = 32; off > 0; off >>= 1) v += __shfl_down(v, off);
    if (lane == 0) logits[n * LL + l] = v + bf;
  }
}

// ---------------- segment softmax (bnodes == identity) ----------------
__global__ __launch_bounds__(64) void k_softmax(const float* __restrict__ logits,
                                                const int* __restrict__ bptr,
                                                float* __restrict__ outN) {
  int b = blockIdx.x / LL, l = blockIdx.x % LL;
  int lane = threadIdx.x;
  int i0 = bptr[b], i1 = bptr[b + 1];
  float m = -1e30f;
  for (int i = i0 + lane; i < i1; i += 64) m = fmaxf(m, logits[i * LL + l]);
#pragma unroll
  for (int off = 32; off > 0; off >>= 1) m = fmaxf(m, __shfl_xor(m, off));
  float s = 0.f;
  for (int i = i0 + lane; i < i1; i += 64) s += expf(logits[i * LL + l] - m);
#pragma unroll
  for (int off = 32; off > 0; off >>= 1) s += __shfl_xor(s, off);
  float inv = 1.f / s;
  for (int i = i0 + lane; i < i1; i += 64) {
    outN[i * LL + l] = expf(logits[i * LL + l] - m) * inv;
  }
}

// ---------------- host ----------------
extern "C" void kernel_launch(void* const* d_in, const int* in_sizes, int n_in,
                              void* d_out, int out_size, void* d_ws, size_t ws_size,
                              hipStream_t stream) {
  const int* nodeTypes = (const int*)d_in[0];
  const int* esrc = (const int*)d_in[1];
  const int* edst = esrc + NE;
  const int* erel = (const int*)d_in[2];
  const int* bs = (const int*)d_in[3];
  const float* seqin = (const float*)d_in[4];
  const int* actin = (const int*)d_in[7];
  const float* embN = (const float*)d_in[8];
  const float* embA = (const float*)d_in[9];
  const float* rgcnW = (const float*)d_in[10];
  const float* rgcnRoot = (const float*)d_in[11];
  const float* rgcnB = (const float*)d_in[12];
  const float* Wih = (const float*)d_in[13];
  const float* Whh = (const float*)d_in[14];
  const float* bih = (const float*)d_in[15];
  const float* bhh = (const float*)d_in[16];
  const float* linA_w = (const float*)d_in[17];
  const float* linA_b = (const float*)d_in[18];
  const float* linAf_w = (const float*)d_in[19];
  const float* linAf_b = (const float*)d_in[20];
  const float* linN_w = (const float*)d_in[21];
  const float* linN_b = (const float*)d_in[22];
  const float* linNf_w = (const float*)d_in[23];
  const float* linNf_b = (const float*)d_in[24];
  const float* fin_w = (const float*)d_in[25];
  const float* fin_b = (const float*)d_in[26];
  const float* finf_w = (const float*)d_in[27];
  const float* finf_b = (const float*)d_in[28];

  float* outA = (float*)d_out;
  float* outNodes = outA + BB * VAx;
  float* outF = outNodes + (size_t)NN * LL;

  char* basep = (char*)d_ws;
  size_t off = 0;
  auto alloc = [&](size_t bytes) -> void* {
    void* p = basep + off;
    off = (off + bytes + 255) & ~(size_t)255;
    return p;
  };

  unsigned int* x = (unsigned int*)alloc(sizeof(unsigned int) * NN * 64);   // bf16 pairs
  unsigned int* x2 = (unsigned int*)alloc(sizeof(unsigned int) * NN * 64);  // bf16 pairs
  float* hG = (float*)alloc(sizeof(float) * BB * HH);
  unsigned short* wcatT = (unsigned short*)alloc(sizeof(unsigned short) * HH * KC);
  unsigned short* linN2bt = (unsigned short*)alloc(sizeof(unsigned short) * HH * HH);
  unsigned short* Wihbt = (unsigned short*)alloc(sizeof(unsigned short) * 3 * HH * HH);
  unsigned short* linN1bt = (unsigned short*)alloc(sizeof(unsigned short) * HH * HH);
  float* WhhT = (float*)alloc(sizeof(float) * HH * 3 * HH);
  float* linAT = (float*)alloc(sizeof(float) * HH * HH);
  float* finT = (float*)alloc(sizeof(float) * HH * HH);
  float* part = (float*)alloc(sizeof(float) * BB * CHK * 25 * HH);
  unsigned short* ig = (unsigned short*)alloc(sizeof(unsigned short) * BB * LL * HH);
  float* gi = (float*)alloc(sizeof(float) * BB * LL * 3 * HH);
  unsigned short* seqb = (unsigned short*)alloc(sizeof(unsigned short) * BB * LL * HH);
  float* part1 = (float*)alloc(sizeof(float) * BB * LL * HH);
  float* part2 = (float*)alloc(sizeof(float) * NN * HH);
  float* logitsB = (float*)alloc(sizeof(float) * NN * LL);
  int* deg = (int*)alloc(sizeof(int) * NN * PS);
  int* cur = (int*)alloc(sizeof(int) * NN * PS);
  int* indptr = (int*)alloc(sizeof(int) * (NN + 1));
  int* esort = (int*)alloc(sizeof(int) * NE);
  int* bptr = (int*)alloc(sizeof(int) * (BB + 1));

  size_t remain = (ws_size > off) ? (ws_size - off) : 0;
  int NCk = NN;
  while ((size_t)NCk * KC * 2 > remain && NCk > 100) NCk >>= 1;
  unsigned int* A = (unsigned int*)alloc((size_t)NCk * (KC / 2) * sizeof(unsigned int));

  // ---- prep (1 launch): weight transforms, embed, zero padded deg ----
  k_prep<<<(PREP_TOTAL + 255) / 256, 256, 0, stream>>>(
      rgcnW, rgcnRoot, wcatT, linN_w, linN2bt, Wih, Wihbt, Whh, WhhT, linA_w, linAT,
      fin_w, finT, linN1bt, nodeTypes, embN, x, deg);

  // ---- CSR: fused count+batch-boundary, scan, scatter ----
  k_count<<<(NE + 255) / 256, 256, 0, stream>>>(edst, deg, bs, bptr);
  k_scane<<<1, 1024, 0, stream>>>(deg, indptr, cur);
  k_scattere<<<(NE + 255) / 256, 256, 0, stream>>>(esrc, edst, erel, cur, esort);

  // ---- 2 RGCN layers (shared weights), bf16 MFMA ----
  const unsigned int* xin = x;
  unsigned int* xout = x2;
  for (int layer = 0; layer < 2; ++layer) {
    for (int n0 = 0; n0 < NN; n0 += NCk) {
      int nc = NN - n0 < NCk ? NN - n0 : NCk;
      k_agg<<<(nc + 3) / 4, 256, 0, stream>>>(xin, indptr, esort, A, n0, nc);
      dim3 g((nc + 63) / 64, 1);
      k_mgemm<1><<<g, 256, 0, stream>>>(
          (const unsigned short*)A, KC, wcatT, KC, rgcnB,
          (void*)((unsigned short*)xout + (size_t)n0 * HH), HH, nc, KC);
    }
    const unsigned int* t = xin;
    xin = xout;
    xout = (unsigned int*)t;
  }
  const unsigned short* nodeEmb = (const unsigned short*)xin;

  // ---- aggS partial/reduce: produces ig (bf16, with SOS) and hG ----
  k_aggS_part<<<BB * CHK, 256, 0, stream>>>(seqin, nodeEmb, bptr, part);
  k_aggS_red<<<(BB * 25 * HH + 255) / 256, 256, 0, stream>>>(part, bptr, embA, actin, ig, hG);

  // ---- heads ----
  k_heads<<<2 * BB, HH, 0, stream>>>(hG, linAT, linA_b, linAf_w, linAf_b, finT, fin_b,
                                     finf_w, finf_b, outA, outF);

  // ---- GRU: gi = ig @ Wih.T + bih via MFMA (N=384 in 3 chunks), then recurrent ----
  {
    dim3 g((BB * LL) / 64, 3);
    k_mgemm<2><<<g, 256, 0, stream>>>(ig, HH, Wihbt, HH, bih, (void*)gi, 3 * HH,
                                      BB * LL, HH);
  }
  k_gru<<<BB, 384, 0, stream>>>(gi, WhhT, bhh, hG, seqb);

  // ---- node logits ----
  {
    dim3 g((BB * LL) / 64, 1);
    k_mgemm<0><<<g, 256, 0, stream>>>(seqb, HH, linN1bt, HH, nullptr, (void*)part1, HH,
                                      BB * LL, HH);
  }
  {
    dim3 g(NN / 64, 1);
    k_mgemm<0><<<g, 256, 0, stream>>>(nodeEmb, HH, linN2bt, HH, nullptr, (void*)part2, HH,
                                      NN, HH);
  }
  k_logits<<<NN / 4, 256, 0, stream>>>(part1, part2, linN_b, linNf_w, linNf_b, bs, logitsB);
  k_softmax<<<BB * LL, 64, 0, stream>>>(logitsB, bptr, outNodes);
}